// Round 2
// baseline (72.906 us; speedup 1.0000x reference)
//
#include <hip/hip_runtime.h>

#define N_ROWS 14400
#define M_COLS 1600
#define KDIM   256

typedef __attribute__((ext_vector_type(8))) short bf16x8;
typedef __attribute__((ext_vector_type(4))) float f32x4;

__device__ __forceinline__ short f2bf(float x) {
  union { float f; unsigned u; } v; v.f = x;
  unsigned r = v.u + 0x7FFFu + ((v.u >> 16) & 1u);   // RNE to bf16
  return (short)(r >> 16);
}

__device__ __forceinline__ void gload_lds16(const void* g, void* l) {
  __builtin_amdgcn_global_load_lds(
      (const __attribute__((address_space(1))) void*)g,
      (__attribute__((address_space(3))) void*)l, 16, 0, 0);
}

// One block per row of prob (normalize+cvt) or emb (cvt only).
__global__ __launch_bounds__(256) void prep_kernel(
    const float* __restrict__ logits, const float* __restrict__ embs,
    short* __restrict__ probB, short* __restrict__ embB) {
  const int b = blockIdx.x, t = threadIdx.x;
  if (b < N_ROWS) {
    float x = logits[(size_t)b * KDIM + t];
    float s = x * x;
#pragma unroll
    for (int o = 32; o > 0; o >>= 1) s += __shfl_down(s, o, 64);
    __shared__ float wsum[4];
    const int lane = t & 63, w = t >> 6;
    if (lane == 0) wsum[w] = s;
    __syncthreads();
    const float tot = wsum[0] + wsum[1] + wsum[2] + wsum[3];
    const float scale = 1.0f / sqrtf(tot);
    probB[(size_t)b * KDIM + t] = f2bf(x * scale);
  } else {
    const int r = b - N_ROWS;
    embB[(size_t)r * KDIM + t] = f2bf(embs[(size_t)r * KDIM + t]);
  }
}

// 128x128 tile GEMM (bf16 MFMA) with fused bbox-L1 + GIoU + sigmoid epilogue.
// LDS fragment tiles are XOR-swizzled: linear global_load_lds dest + pre-swizzled
// global source granule; reads XOR with (row&7). Kills the 16-way bank conflict.
__global__ __launch_bounds__(256, 4) void cost_kernel(
    const short* __restrict__ probB, const short* __restrict__ embB,
    const float* __restrict__ pbox, const float* __restrict__ tbox,
    float* __restrict__ out) {
  __shared__ short As[128 * 64];
  __shared__ short Bs[128 * 64];

  const int t = threadIdx.x;
  const int lane = t & 63;
  const int wid = t >> 6;
  const int wr = wid >> 1;          // wave row 0..1 (64-row band)
  const int wc = wid & 1;           // wave col 0..1 (64-col band)
  const int rowBase = blockIdx.y * 128;   // N (pred) direction
  const int colBase = blockIdx.x * 128;   // M (tgt) direction

  f32x4 acc[4][4];
#pragma unroll
  for (int i = 0; i < 4; ++i)
#pragma unroll
    for (int j = 0; j < 4; ++j) acc[i][j] = (f32x4){0.f, 0.f, 0.f, 0.f};

  // Pre-swizzled source granule: lane l stages LDS bytes l*16 of its 1024B
  // chunk (rows l>>3, slots l&7); fetch granule (l&7)^(l>>3) so that the
  // swizzled READ (granule ^ row&7) sees the right data.
  const int swz_gran = (lane & 7) ^ (lane >> 3);

  // K-loop: 4 tiles of BK=64.
  for (int kt = 0; kt < 4; ++kt) {
    const int k0 = kt * 64 + swz_gran * 8;  // element offset in K per lane
#pragma unroll
    for (int i = 0; i < 4; ++i) {
      const int rr = wid * 32 + i * 8 + (lane >> 3);   // row within tile
      int gr = rowBase + rr; if (gr > N_ROWS - 1) gr = N_ROWS - 1;
      gload_lds16(probB + (size_t)gr * KDIM + k0, As + (wid * 32 + i * 8) * 64);
      int gc = colBase + rr; if (gc > M_COLS - 1) gc = M_COLS - 1;
      gload_lds16(embB + (size_t)gc * KDIM + k0, Bs + (wid * 32 + i * 8) * 64);
    }
    __syncthreads();
#pragma unroll
    for (int kk = 0; kk < 2; ++kk) {
      bf16x8 af[4], bfr[4];
      const int g = kk * 4 + (lane >> 4);   // 16B granule index 0..7
#pragma unroll
      for (int mi = 0; mi < 4; ++mi) {
        const int row = wr * 64 + mi * 16 + (lane & 15);
        af[mi] = *(const bf16x8*)(As + row * 64 + ((g ^ (row & 7)) * 8));
      }
#pragma unroll
      for (int ni = 0; ni < 4; ++ni) {
        const int row = wc * 64 + ni * 16 + (lane & 15);
        bfr[ni] = *(const bf16x8*)(Bs + row * 64 + ((g ^ (row & 7)) * 8));
      }
#pragma unroll
      for (int mi = 0; mi < 4; ++mi)
#pragma unroll
        for (int ni = 0; ni < 4; ++ni)
          acc[mi][ni] = __builtin_amdgcn_mfma_f32_16x16x32_bf16(
              af[mi], bfr[ni], acc[mi][ni], 0, 0, 0);
    }
    __syncthreads();
  }

  // Fused epilogue: C = L1 + relu(dot) - GIoU ; out = sigmoid(C).
  // Box data read directly from global (L2-resident, broadcast across lanes).
  const float LOG2E = 1.44269504f;
#pragma unroll
  for (int mi = 0; mi < 4; ++mi) {
    float rcx[4], rcy[4], rw[4], rh[4];
    float rx1[4], ry1[4], rx2[4], ry2[4], rar[4];
    int gnv[4];
#pragma unroll
    for (int j = 0; j < 4; ++j) {
      const int gn = rowBase + wr * 64 + mi * 16 + (lane >> 4) * 4 + j;
      gnv[j] = gn;
      const int rn = gn < N_ROWS ? gn : N_ROWS - 1;
      const float4 bb = ((const float4*)pbox)[rn];
      rcx[j] = bb.x; rcy[j] = bb.y; rw[j] = bb.z; rh[j] = bb.w;
      rx1[j] = fmaf(-0.5f, bb.z, bb.x);
      ry1[j] = fmaf(-0.5f, bb.w, bb.y);
      rx2[j] = fmaf(0.5f, bb.z, bb.x);
      ry2[j] = fmaf(0.5f, bb.w, bb.y);
      rar[j] = bb.z * bb.w;
    }
#pragma unroll
    for (int ni = 0; ni < 4; ++ni) {
      const int gm = colBase + wc * 64 + ni * 16 + (lane & 15);
      const int cm = gm < M_COLS ? gm : M_COLS - 1;
      const float4 cb4 = ((const float4*)tbox)[cm];
      const float ccx = cb4.x, ccy = cb4.y, cw = cb4.z, ch = cb4.w;
      const float cx1 = fmaf(-0.5f, cw, ccx);
      const float cy1 = fmaf(-0.5f, ch, ccy);
      const float cx2 = fmaf(0.5f, cw, ccx);
      const float cy2 = fmaf(0.5f, ch, ccy);
      const float car = cw * ch;
      const bool mok = (gm < M_COLS);
#pragma unroll
      for (int j = 0; j < 4; ++j) {
        const float cc = fmaxf(acc[mi][ni][j], 0.0f);
        const float l1 = fabsf(rcx[j] - ccx) + fabsf(rcy[j] - ccy) +
                         fabsf(rw[j] - cw) + fabsf(rh[j] - ch);
        const float ltx = fmaxf(rx1[j], cx1);
        const float lty = fmaxf(ry1[j], cy1);
        const float rbx = fminf(rx2[j], cx2);
        const float rby = fminf(ry2[j], cy2);
        const float iw = fmaxf(rbx - ltx, 0.f);
        const float ih = fmaxf(rby - lty, 0.f);
        const float inter = iw * ih;
        const float uni = rar[j] + car - inter;
        const float ex = fmaxf(rx2[j], cx2) - fminf(rx1[j], cx1);
        const float ey = fmaxf(ry2[j], cy2) - fminf(ry1[j], cy1);
        const float earea = ex * ey;
        // C = l1 + cc - (iou - (earea-uni)/earea) = l1 + cc + 1 - inter/uni - uni/earea
        const float Cv = l1 + cc + 1.0f
                         - inter * __builtin_amdgcn_rcpf(uni)
                         - uni * __builtin_amdgcn_rcpf(earea);
        const float sg = __builtin_amdgcn_rcpf(
            1.0f + __builtin_amdgcn_exp2f(-LOG2E * Cv));
        if (mok && gnv[j] < N_ROWS)
          out[(size_t)gnv[j] * M_COLS + gm] = sg;
      }
    }
  }
}

extern "C" void kernel_launch(void* const* d_in, const int* in_sizes, int n_in,
                              void* d_out, int out_size, void* d_ws, size_t ws_size,
                              hipStream_t stream) {
  const float* logits = (const float*)d_in[0];   // [16,900,256]
  const float* pbox   = (const float*)d_in[1];   // [16,900,4]
  const float* embs   = (const float*)d_in[2];   // [1600,256]
  const float* tbox   = (const float*)d_in[3];   // [1600,4]
  float* out = (float*)d_out;                    // [16,900,1600]

  short* probB = (short*)d_ws;                         // 14400*256 bf16
  short* embB  = probB + (size_t)N_ROWS * KDIM;        // 1600*256 bf16

  prep_kernel<<<N_ROWS + M_COLS, 256, 0, stream>>>(logits, embs, probB, embB);

  dim3 grid((M_COLS + 127) / 128, (N_ROWS + 127) / 128);  // (13, 113)
  cost_kernel<<<grid, 256, 0, stream>>>(probB, embB, pbox, tbox, out);
}

// Round 3
// 58.778 us; speedup vs baseline: 1.2403x; 1.2403x over previous
//
#include <hip/hip_runtime.h>

#define N_ROWS 14400
#define M_COLS 1600
#define KDIM   256
#define GRID_X 13
#define GRID_Y 113
#define NWG    (GRID_X * GRID_Y)

typedef __attribute__((ext_vector_type(8))) short bf16x8;
typedef __attribute__((ext_vector_type(4))) float f32x4;

__device__ __forceinline__ short f2bf(float x) {
  union { float f; unsigned u; } v; v.f = x;
  unsigned r = v.u + 0x7FFFu + ((v.u >> 16) & 1u);   // RNE to bf16
  return (short)(r >> 16);
}

__device__ __forceinline__ void gload_lds16(const void* g, void* l) {
  __builtin_amdgcn_global_load_lds(
      (const __attribute__((address_space(1))) void*)g,
      (__attribute__((address_space(3))) void*)l, 16, 0, 0);
}

// One block per row of prob (normalize+cvt) or emb (cvt only).
__global__ __launch_bounds__(256) void prep_kernel(
    const float* __restrict__ logits, const float* __restrict__ embs,
    short* __restrict__ probB, short* __restrict__ embB) {
  const int b = blockIdx.x, t = threadIdx.x;
  if (b < N_ROWS) {
    float x = logits[(size_t)b * KDIM + t];
    float s = x * x;
#pragma unroll
    for (int o = 32; o > 0; o >>= 1) s += __shfl_down(s, o, 64);
    __shared__ float wsum[4];
    const int lane = t & 63, w = t >> 6;
    if (lane == 0) wsum[w] = s;
    __syncthreads();
    const float tot = wsum[0] + wsum[1] + wsum[2] + wsum[3];
    const float scale = 1.0f / sqrtf(tot);
    probB[(size_t)b * KDIM + t] = f2bf(x * scale);
  } else {
    const int r = b - N_ROWS;
    embB[(size_t)r * KDIM + t] = f2bf(embs[(size_t)r * KDIM + t]);
  }
}

// 128x128 tile GEMM (bf16 MFMA) with fused bbox-L1 + GIoU + sigmoid epilogue.
// - LDS GEMM tiles XOR-swizzled (linear gload_lds dest + pre-swizzled global
//   source granule + swizzled read) -> 0 bank conflicts.
// - Box data staged in LDS (stride 12 floats: broadcast / 2-way reads).
// - Bijective XCD-aware block swizzle: contiguous row-bands per XCD for A reuse.
__global__ __launch_bounds__(256) void cost_kernel(
    const short* __restrict__ probB, const short* __restrict__ embB,
    const float* __restrict__ pbox, const float* __restrict__ tbox,
    float* __restrict__ out) {
  __shared__ short As[128 * 64];
  __shared__ short Bs[128 * 64];
  __shared__ float rowd[128 * 12];
  __shared__ float cold[128 * 12];

  const int t = threadIdx.x;
  const int lane = t & 63;
  const int wid = t >> 6;
  const int wr = wid >> 1;          // wave row 0..1 (64-row band)
  const int wc = wid & 1;           // wave col 0..1 (64-col band)

  // Bijective XCD swizzle (m204): 8 XCDs, chunk q=NWG/8 (+1 for first r).
  const int orig = blockIdx.x;
  const int xcd = orig & 7;
  const int rem = orig >> 3;
  const int q = NWG >> 3, r = NWG & 7;
  const int wgid = (xcd < r ? xcd * (q + 1) : r * (q + 1) + (xcd - r) * q) + rem;
  const int bx = wgid % GRID_X;
  const int by = wgid / GRID_X;
  const int rowBase = by * 128;     // N (pred) direction
  const int colBase = bx * 128;     // M (tgt) direction

  // Stage per-tile box data: [cx,cy,w,h, x1,y1,x2,y2, area] (12-float stride).
  {
    const bool isRow = (t < 128);
    const int idx = isRow ? (rowBase + t) : (colBase + t - 128);
    const int lim = isRow ? N_ROWS : M_COLS;
    const int cidx = idx < lim ? idx : lim - 1;
    const float4 bb = isRow ? ((const float4*)pbox)[cidx]
                            : ((const float4*)tbox)[cidx];
    float* d = (isRow ? rowd + t * 12 : cold + (t - 128) * 12);
    d[0] = bb.x; d[1] = bb.y; d[2] = bb.z; d[3] = bb.w;
    d[4] = fmaf(-0.5f, bb.z, bb.x);
    d[5] = fmaf(-0.5f, bb.w, bb.y);
    d[6] = fmaf(0.5f, bb.z, bb.x);
    d[7] = fmaf(0.5f, bb.w, bb.y);
    d[8] = bb.z * bb.w;
  }

  f32x4 acc[4][4];
#pragma unroll
  for (int i = 0; i < 4; ++i)
#pragma unroll
    for (int j = 0; j < 4; ++j) acc[i][j] = (f32x4){0.f, 0.f, 0.f, 0.f};

  // Pre-swizzled source granule (see round-2 notes): lane l stages granule
  // (l&7)^(l>>3) so the swizzled READ (g ^ row&7) sees linear data.
  const int swz_gran = (lane & 7) ^ (lane >> 3);

  // K-loop: 4 tiles of BK=64.
  for (int kt = 0; kt < 4; ++kt) {
    const int k0 = kt * 64 + swz_gran * 8;
#pragma unroll
    for (int i = 0; i < 4; ++i) {
      const int rr = wid * 32 + i * 8 + (lane >> 3);
      int gr = rowBase + rr; if (gr > N_ROWS - 1) gr = N_ROWS - 1;
      gload_lds16(probB + (size_t)gr * KDIM + k0, As + (wid * 32 + i * 8) * 64);
      int gc = colBase + rr; if (gc > M_COLS - 1) gc = M_COLS - 1;
      gload_lds16(embB + (size_t)gc * KDIM + k0, Bs + (wid * 32 + i * 8) * 64);
    }
    __syncthreads();
#pragma unroll
    for (int kk = 0; kk < 2; ++kk) {
      bf16x8 af[4], bfr[4];
      const int g = kk * 4 + (lane >> 4);   // 16B granule index 0..7
#pragma unroll
      for (int mi = 0; mi < 4; ++mi) {
        const int row = wr * 64 + mi * 16 + (lane & 15);
        af[mi] = *(const bf16x8*)(As + row * 64 + ((g ^ (row & 7)) * 8));
      }
#pragma unroll
      for (int ni = 0; ni < 4; ++ni) {
        const int row = wc * 64 + ni * 16 + (lane & 15);
        bfr[ni] = *(const bf16x8*)(Bs + row * 64 + ((g ^ (row & 7)) * 8));
      }
#pragma unroll
      for (int mi = 0; mi < 4; ++mi)
#pragma unroll
        for (int ni = 0; ni < 4; ++ni)
          acc[mi][ni] = __builtin_amdgcn_mfma_f32_16x16x32_bf16(
              af[mi], bfr[ni], acc[mi][ni], 0, 0, 0);
    }
    __syncthreads();
  }

  // Fused epilogue: C = l1 + relu(dot) + 1 - inter/uni - uni/earea; sigmoid.
  const float LOG2E = 1.44269504f;
#pragma unroll
  for (int mi = 0; mi < 4; ++mi) {
    f32x4 r0[4], r1[4];
    float ra[4];
    int gnv[4];
#pragma unroll
    for (int j = 0; j < 4; ++j) {
      const int rloc = wr * 64 + mi * 16 + (lane >> 4) * 4 + j;
      gnv[j] = rowBase + rloc;
      const float* rd = rowd + rloc * 12;
      r0[j] = *(const f32x4*)(rd);
      r1[j] = *(const f32x4*)(rd + 4);
      ra[j] = rd[8];
    }
#pragma unroll
    for (int ni = 0; ni < 4; ++ni) {
      const int mloc = wc * 64 + ni * 16 + (lane & 15);
      const float* cd = cold + mloc * 12;
      const f32x4 c0 = *(const f32x4*)(cd);
      const f32x4 c1 = *(const f32x4*)(cd + 4);
      const float ca = cd[8];
      const int gm = colBase + mloc;
      const bool mok = (gm < M_COLS);
#pragma unroll
      for (int j = 0; j < 4; ++j) {
        const float cc = fmaxf(acc[mi][ni][j], 0.0f);
        const float l1 = fabsf(r0[j][0] - c0[0]) + fabsf(r0[j][1] - c0[1]) +
                         fabsf(r0[j][2] - c0[2]) + fabsf(r0[j][3] - c0[3]);
        const float ltx = fmaxf(r1[j][0], c1[0]);
        const float lty = fmaxf(r1[j][1], c1[1]);
        const float rbx = fminf(r1[j][2], c1[2]);
        const float rby = fminf(r1[j][3], c1[3]);
        const float iw = fmaxf(rbx - ltx, 0.f);
        const float ih = fmaxf(rby - lty, 0.f);
        const float inter = iw * ih;
        const float uni = ra[j] + ca - inter;
        const float ex = fmaxf(r1[j][2], c1[2]) - fminf(r1[j][0], c1[0]);
        const float ey = fmaxf(r1[j][3], c1[3]) - fminf(r1[j][1], c1[1]);
        const float earea = ex * ey;
        const float Cv = l1 + cc + 1.0f
                         - inter * __builtin_amdgcn_rcpf(uni)
                         - uni * __builtin_amdgcn_rcpf(earea);
        const float sg = __builtin_amdgcn_rcpf(
            1.0f + __builtin_amdgcn_exp2f(-LOG2E * Cv));
        if (mok && gnv[j] < N_ROWS)
          out[(size_t)gnv[j] * M_COLS + gm] = sg;
      }
    }
  }
}

extern "C" void kernel_launch(void* const* d_in, const int* in_sizes, int n_in,
                              void* d_out, int out_size, void* d_ws, size_t ws_size,
                              hipStream_t stream) {
  const float* logits = (const float*)d_in[0];   // [16,900,256]
  const float* pbox   = (const float*)d_in[1];   // [16,900,4]
  const float* embs   = (const float*)d_in[2];   // [1600,256]
  const float* tbox   = (const float*)d_in[3];   // [1600,4]
  float* out = (float*)d_out;                    // [16,900,1600]

  short* probB = (short*)d_ws;                         // 14400*256 bf16
  short* embB  = probB + (size_t)N_ROWS * KDIM;        // 1600*256 bf16

  prep_kernel<<<N_ROWS + M_COLS, 256, 0, stream>>>(logits, embs, probB, embB);

  cost_kernel<<<NWG, 256, 0, stream>>>(probB, embB, pbox, tbox, out);
}